// Round 6
// baseline (319.823 us; speedup 1.0000x reference)
//
#include <hip/hip_runtime.h>
#include <hip/hip_bf16.h>
#include <math.h>

// B=64, M=1, L=E=4096, H=64, DK=64.
// Barrier-free register-streaming skinny GEMM:
//  - W (HBM, read once) -> regs, scalar dword x8 per chunk, 2-chunk prefetch
//  - A (1 MB hi+lo, L2-hot) pre-PACKED in MFMA-fragment order so every
//    fragment load is one lane-contiguous 1KB global_load_dwordx4.
// No LDS, no barriers, no inline asm. bf16 split-precision MFMA (hi/lo).

#define TL 4096
#define NB 64
#define KSQ 4   // k-splits for QKV projections
#define KSO 8   // k-splits for output GEMM

typedef float f32x4 __attribute__((ext_vector_type(4)));
typedef short bf16x8 __attribute__((ext_vector_type(8)));
typedef unsigned int uint32;
typedef unsigned short u16;

union B8 { uint32 u[4]; bf16x8 v; };

// Split two fp32 into packed hi-bf16 pair and lo-bf16 pair (truncation).
__device__ __forceinline__ void split_pair(float f0, float f1, uint32& hp,
                                           uint32& lp) {
  uint32 u0 = __float_as_uint(f0), u1 = __float_as_uint(f1);
  hp = (u0 >> 16) | (u1 & 0xffff0000u);
  float l0 = f0 - __uint_as_float(u0 & 0xffff0000u);
  float l1 = f1 - __uint_as_float(u1 & 0xffff0000u);
  lp = (__float_as_uint(l0) >> 16) | (__float_as_uint(l1) & 0xffff0000u);
}

// Packed-A index: fragment fi = t*4+rt (t = K32 chunk, rt = 16-row group),
// lane = kg*16+l15 holds rows rt*16+l15, k = t*32+kg*8+e, e=0..7.
// u16 offset = (fi*64 + lane)*8.

// ---------------------------------------------------------------------------
// prep: fp32 X[64][4096] -> packed Ah, Al (bf16 fragment order)
// One thread = one (fi, lane) = 8 consecutive k of one row.
// ---------------------------------------------------------------------------
struct Ptrs3 { const float* X[3]; u16* H[3]; u16* L[3]; };

__global__ __launch_bounds__(256) void prep_kernel(Ptrs3 p) {
  const int m = blockIdx.y;
  const int fid = blockIdx.x * 256 + threadIdx.x;  // 0..32767
  const int lane = fid & 63, fi = fid >> 6;        // fi 0..511
  const int t = fi >> 2, rt = fi & 3;
  const int row = rt * 16 + (lane & 15);
  const int k0 = t * 32 + (lane >> 4) * 8;
  const float* src = p.X[m] + (size_t)row * TL + k0;
  const float4 f0 = *reinterpret_cast<const float4*>(src);
  const float4 f1 = *reinterpret_cast<const float4*>(src + 4);
  uint4 h, l;
  split_pair(f0.x, f0.y, h.x, l.x);
  split_pair(f0.z, f0.w, h.y, l.y);
  split_pair(f1.x, f1.y, h.z, l.z);
  split_pair(f1.z, f1.w, h.w, l.w);
  *reinterpret_cast<uint4*>(p.H[m] + (size_t)fid * 8) = h;
  *reinterpret_cast<uint4*>(p.L[m] + (size_t)fid * 8) = l;
}

// ---------------------------------------------------------------------------
// GEMM: P[ks][64][4096] partial = X[64][krange] @ W[krange][4096]
// Block: 4 waves (256 thr), 64 cols (16/wave), all 64 rows, KR = TL/KSplit.
// Chunk = K32: 8 B dwords (HBM) + 8 packed-A dwordx4 (L2, 1KB each).
// ---------------------------------------------------------------------------
struct GemmArgs {
  const u16* Ah[3];
  const u16* Al[3];
  const float* W[3];
  float* P[3];
};

template <int KSplit, int NMat>
__global__ __launch_bounds__(256, 4) void mfma_gemm(GemmArgs ga) {
  constexpr int KR = TL / KSplit;   // K range per block
  constexpr int NC = KR / 32;       // K32 chunks (32 or 16, even)
  constexpr int NWG = NMat * KSplit * 64;
  static_assert(NWG % 8 == 0, "xcd swizzle needs NWG%8==0");

  const int tid = threadIdx.x;
  const int lane = tid & 63;
  const int w = tid >> 6;                    // wave 0..3
  const int l15 = lane & 15, kg = lane >> 4;

  // Bijective XCD swizzle: contiguous block range per XCD -> the shared
  // packed-A slice stays resident in that XCD's L2.
  const int swz = (blockIdx.x & 7) * (NWG / 8) + (blockIdx.x >> 3);
  const int mat = swz / (KSplit * 64);
  const int r = swz % (KSplit * 64);
  const int ks = r >> 6;
  const int ct = r & 63;
  const int k0 = ks * KR;
  const int tg0 = ks * NC;                   // global chunk base
  const int colg = ct * 64 + w * 16;         // this wave's 16-col base

  const float* Wm = ga.W[mat];
  const u16* Agh = ga.Ah[mat];
  const u16* Agl = ga.Al[mat];

  const float* wp0 = Wm + (size_t)(k0 + kg * 8) * TL + colg + l15;

  auto LOADA = [&](bf16x8 (&h)[4], bf16x8 (&l)[4], int t) {
    const uint32 base = ((uint32)(tg0 + t) * 4 * 64 + (uint32)lane) * 8;
#pragma unroll
    for (int rt = 0; rt < 4; ++rt) {
      h[rt] = *(const bf16x8*)(Agh + base + (uint32)rt * 512);
      l[rt] = *(const bf16x8*)(Agl + base + (uint32)rt * 512);
    }
  };

  auto LOADB = [&](float (&f)[8], int t) {
    const float* wp = wp0 + (size_t)t * 32 * TL;
#pragma unroll
    for (int e = 0; e < 8; ++e) f[e] = wp[(size_t)e * TL];
  };

  f32x4 acc[4] = {};

  auto COMPUTE = [&](const bf16x8 (&h)[4], const bf16x8 (&l)[4],
                     const float (&f)[8]) {
    B8 bh, bl;
#pragma unroll
    for (int e = 0; e < 4; ++e)
      split_pair(f[2 * e], f[2 * e + 1], bh.u[e], bl.u[e]);
#pragma unroll
    for (int rt = 0; rt < 4; ++rt) {
      acc[rt] = __builtin_amdgcn_mfma_f32_16x16x32_bf16(h[rt], bh.v, acc[rt], 0, 0, 0);
      acc[rt] = __builtin_amdgcn_mfma_f32_16x16x32_bf16(h[rt], bl.v, acc[rt], 0, 0, 0);
      acc[rt] = __builtin_amdgcn_mfma_f32_16x16x32_bf16(l[rt], bh.v, acc[rt], 0, 0, 0);
    }
  };

  // Static double-buffered registers (rule #20: no runtime indexing).
  bf16x8 ah0[4], al0[4], ah1[4], al1[4];
  float b0[8], b1[8];

  LOADA(ah0, al0, 0); LOADB(b0, 0);
  LOADA(ah1, al1, 1); LOADB(b1, 1);

#pragma unroll 1
  for (int t = 0; t < NC - 2; t += 2) {
    COMPUTE(ah0, al0, b0);
    LOADA(ah0, al0, t + 2);
    LOADB(b0, t + 2);
    COMPUTE(ah1, al1, b1);
    LOADA(ah1, al1, t + 3);
    LOADB(b1, t + 3);
  }
  COMPUTE(ah0, al0, b0);
  COMPUTE(ah1, al1, b1);

  // C/D: col = lane&15, row = (lane>>4)*4 + reg (per 16-row tile rt)
  float* Pp = ga.P[mat] + ((size_t)ks * NB) * TL + colg + l15;
#pragma unroll
  for (int rt = 0; rt < 4; ++rt)
#pragma unroll
    for (int j = 0; j < 4; ++j)
      Pp[(size_t)(rt * 16 + kg * 4 + j) * TL] = acc[rt][j];
}

// ---------------------------------------------------------------------------
// dist[b,h] = softmax_h(cossim(qh[b,h,:], kh[b,h,:])); sums KSQ partials+bias.
// ---------------------------------------------------------------------------
__global__ __launch_bounds__(64) void dist_kernel(
    const float* __restrict__ Pq, const float* __restrict__ Pk,
    const float* __restrict__ bq, const float* __restrict__ bk,
    float* __restrict__ dist) {
  const int b = blockIdx.x;
  const int h = threadIdx.x;
  float num = 0.f, qq = 0.f, kk = 0.f;
#pragma unroll
  for (int d = 0; d < 64; d += 4) {
    f32x4 qv = *(const f32x4*)&bq[h * 64 + d];
    f32x4 kv = *(const f32x4*)&bk[h * 64 + d];
#pragma unroll
    for (int s = 0; s < KSQ; ++s) {
      qv += *(const f32x4*)&Pq[((size_t)s * NB + b) * TL + h * 64 + d];
      kv += *(const f32x4*)&Pk[((size_t)s * NB + b) * TL + h * 64 + d];
    }
#pragma unroll
    for (int e = 0; e < 4; ++e) {
      num += qv[e] * kv[e];
      qq += qv[e] * qv[e];
      kk += kv[e] * kv[e];
    }
  }
  const float den = fmaxf(sqrtf(qq) * sqrtf(kk), 1e-8f);
  float s = num / den;
  float m = s;
#pragma unroll
  for (int off = 32; off; off >>= 1) m = fmaxf(m, __shfl_xor(m, off));
  const float e = expf(s - m);
  float sum = e;
#pragma unroll
  for (int off = 32; off; off >>= 1) sum += __shfl_xor(sum, off);
  dist[b * 64 + h] = e / sum;
}

// ---------------------------------------------------------------------------
// attn row i: vrow = sum(Pv parts)+bv; attn[i,c] = sum_h ds[j,h]*vrow[h*64+d]
// Emits hi/lo bf16 in PACKED fragment order (A-operand of the output GEMM).
// ---------------------------------------------------------------------------
__global__ __launch_bounds__(256) void attn_kernel(
    const float* __restrict__ Pv, const float* __restrict__ bv,
    const float* __restrict__ dist, u16* __restrict__ Ah,
    u16* __restrict__ Al) {
  const int i = blockIdx.x;
  __shared__ float vrow[TL];
  __shared__ float ds[NB * NB];
  const int tid = threadIdx.x;
#pragma unroll
  for (int f = tid; f < 1024; f += 256) {
    f32x4 v = *(const f32x4*)&bv[f * 4];
#pragma unroll
    for (int s = 0; s < KSQ; ++s)
      v += *(const f32x4*)&Pv[((size_t)s * NB + i) * TL + f * 4];
    *reinterpret_cast<f32x4*>(&vrow[f * 4]) = v;
    *reinterpret_cast<f32x4*>(&ds[f * 4]) =
        *reinterpret_cast<const f32x4*>(&dist[f * 4]);
  }
  __syncthreads();
  const int rt = i >> 4, l15r = i & 15;
#pragma unroll
  for (int s = 0; s < 16; ++s) {
    const int c = tid + 256 * s;
    const int j = c >> 6, d = c & 63;
    float sum = 0.f;
#pragma unroll
    for (int h = 0; h < 64; ++h) sum += ds[j * 64 + h] * vrow[h * 64 + d];
    const uint32 u = __float_as_uint(sum);
    const float lo = sum - __uint_as_float(u & 0xffff0000u);
    // packed index: t=c>>5, kg=(c>>3)&3, e=c&7
    const uint32 off =
        (((uint32)(c >> 5) * 4 + rt) * 64 + ((c >> 3) & 3) * 16 + l15r) * 8 +
        (c & 7);
    Ah[off] = (u16)(u >> 16);
    Al[off] = (u16)(__float_as_uint(lo) >> 16);
  }
}

// out = sum over KSO partials + bo
__global__ __launch_bounds__(256) void reduce_kernel(
    const float* __restrict__ Po, const float* __restrict__ bo,
    float* __restrict__ out) {
  const int idx = (blockIdx.x * 256 + threadIdx.x) * 4;
  f32x4 v = *(const f32x4*)&bo[idx & (TL - 1)];
#pragma unroll
  for (int s = 0; s < KSO; ++s)
    v += *(const f32x4*)&Po[(size_t)s * NB * TL + idx];
  *reinterpret_cast<f32x4*>(&out[idx]) = v;
}

extern "C" void kernel_launch(void* const* d_in, const int* in_sizes, int n_in,
                              void* d_out, int out_size, void* d_ws,
                              size_t ws_size, hipStream_t stream) {
  const float* q  = (const float*)d_in[0];
  const float* k  = (const float*)d_in[1];
  const float* v  = (const float*)d_in[2];
  const float* Wq = (const float*)d_in[3];
  const float* bq = (const float*)d_in[4];
  const float* Wk = (const float*)d_in[5];
  const float* bk = (const float*)d_in[6];
  const float* Wv = (const float*)d_in[7];
  const float* bv = (const float*)d_in[8];
  const float* Wo = (const float*)d_in[9];
  const float* bo = (const float*)d_in[10];
  float* out = (float*)d_out;

  char* ws = (char*)d_ws;
  const size_t HB = 512u * 1024u;
  u16* qAh = (u16*)(ws + 0 * HB);
  u16* qAl = (u16*)(ws + 1 * HB);
  u16* kAh = (u16*)(ws + 2 * HB);
  u16* kAl = (u16*)(ws + 3 * HB);
  u16* vAh = (u16*)(ws + 4 * HB);
  u16* vAl = (u16*)(ws + 5 * HB);
  u16* aAh = (u16*)(ws + 6 * HB);
  u16* aAl = (u16*)(ws + 7 * HB);
  float* Pq = (float*)(ws + (4u << 20));   // 4 MiB (KSQ=4 partials)
  float* Pk = (float*)(ws + (8u << 20));   // 4 MiB
  float* Pv = (float*)(ws + (12u << 20));  // 4 MiB
  // Po (KSO=8, 8 MiB) aliases [Pq,Pk]: both fully consumed before O-GEMM.
  float* Po = Pq;
  float* dist = (float*)(ws + (16u << 20));  // 16 KiB

  // 1. split q,k,v into packed hi/lo bf16 fragments
  Ptrs3 p3;
  p3.X[0] = q; p3.X[1] = k; p3.X[2] = v;
  p3.H[0] = qAh; p3.H[1] = kAh; p3.H[2] = vAh;
  p3.L[0] = qAl; p3.L[1] = kAl; p3.L[2] = vAl;
  prep_kernel<<<dim3(128, 3), 256, 0, stream>>>(p3);

  // 2. QKV projections: 3 mats x KSQ x 64 coltiles = 768 blocks (3/CU)
  GemmArgs gq;
  gq.Ah[0] = qAh; gq.Ah[1] = kAh; gq.Ah[2] = vAh;
  gq.Al[0] = qAl; gq.Al[1] = kAl; gq.Al[2] = vAl;
  gq.W[0] = Wq; gq.W[1] = Wk; gq.W[2] = Wv;
  gq.P[0] = Pq; gq.P[1] = Pk; gq.P[2] = Pv;
  mfma_gemm<KSQ, 3><<<3 * KSQ * 64, 256, 0, stream>>>(gq);

  // 3. cosine-sim + softmax
  dist_kernel<<<NB, 64, 0, stream>>>(Pq, Pk, bq, bk, dist);

  // 4. attention mix -> packed bf16 hi/lo attn
  attn_kernel<<<NB, 256, 0, stream>>>(Pv, bv, dist, aAh, aAl);

  // 5. output GEMM: KSO x 64 coltiles = 512 blocks (2/CU)
  GemmArgs go;
  go.Ah[0] = aAh; go.Ah[1] = aAh; go.Ah[2] = aAh;
  go.Al[0] = aAl; go.Al[1] = aAl; go.Al[2] = aAl;
  go.W[0] = Wo; go.W[1] = Wo; go.W[2] = Wo;
  go.P[0] = Po; go.P[1] = Po; go.P[2] = Po;
  mfma_gemm<KSO, 1><<<KSO * 64, 256, 0, stream>>>(go);

  // 6. final reduce + bias
  reduce_kernel<<<256, 256, 0, stream>>>(Po, bo, out);
}

// Round 7
// 113.217 us; speedup vs baseline: 2.8249x; 2.8249x over previous
//
#include <hip/hip_runtime.h>
#include <hip/hip_bf16.h>
#include <math.h>

// B=64, M=1, L=E=4096, H=64, DK=64.
// LDS-staged skinny GEMM, ALL staging via global_load_lds (homogeneous vmem
// stream -> counted vmcnt is race-free), triple-buffered K32x64col tiles,
// 2-deep prefetch, s_waitcnt vmcnt(8)+s_barrier (never a full drain in-loop).
// bf16 split-precision MFMA (hi/lo, 3 products). A pre-packed in MFMA
// fragment order so A-staging is linear.

#define TL 4096
#define NB 64
#define KSQ 4   // k-splits for QKV projections
#define KSO 8   // k-splits for output GEMM

typedef float f32x4 __attribute__((ext_vector_type(4)));
typedef short bf16x8 __attribute__((ext_vector_type(8)));
typedef unsigned int uint32;
typedef unsigned short u16;

union B8 { uint32 u[4]; bf16x8 v; };

// global_load_lds: per-lane global src, LDS dest = wave-uniform base + lane*16.
#define GLOAD_LDS(g, l)                                                        \
  __builtin_amdgcn_global_load_lds(                                           \
      (const __attribute__((address_space(1))) void*)(g),                     \
      (__attribute__((address_space(3))) void*)(l), 16, 0, 0)

// Split two fp32 into packed hi-bf16 pair and lo-bf16 pair (truncation).
__device__ __forceinline__ void split_pair(float f0, float f1, uint32& hp,
                                           uint32& lp) {
  uint32 u0 = __float_as_uint(f0), u1 = __float_as_uint(f1);
  hp = (u0 >> 16) | (u1 & 0xffff0000u);
  float l0 = f0 - __uint_as_float(u0 & 0xffff0000u);
  float l1 = f1 - __uint_as_float(u1 & 0xffff0000u);
  lp = (__float_as_uint(l0) >> 16) | (__float_as_uint(l1) & 0xffff0000u);
}

// Packed-A index: fragment fi = T*4+rt (T = global K32 chunk, rt = 16-row
// group), lane = kg*16+l15 holds row rt*16+l15, k = T*32+kg*8+e, e=0..7.
// u16 offset = (fi*64 + lane)*8.

// ---------------------------------------------------------------------------
// prep: fp32 X[64][4096] -> packed Ah, Al (bf16 fragment order)
// ---------------------------------------------------------------------------
struct Ptrs3 { const float* X[3]; u16* H[3]; u16* L[3]; };

__global__ __launch_bounds__(256) void prep_kernel(Ptrs3 p) {
  const int m = blockIdx.y;
  const int fid = blockIdx.x * 256 + threadIdx.x;  // 0..32767
  const int lane = fid & 63, fi = fid >> 6;        // fi 0..511
  const int t = fi >> 2, rt = fi & 3;
  const int row = rt * 16 + (lane & 15);
  const int k0 = t * 32 + (lane >> 4) * 8;
  const float* src = p.X[m] + (size_t)row * TL + k0;
  const float4 f0 = *reinterpret_cast<const float4*>(src);
  const float4 f1 = *reinterpret_cast<const float4*>(src + 4);
  uint4 h, l;
  split_pair(f0.x, f0.y, h.x, l.x);
  split_pair(f0.z, f0.w, h.y, l.y);
  split_pair(f1.x, f1.y, h.z, l.z);
  split_pair(f1.z, f1.w, h.w, l.w);
  *reinterpret_cast<uint4*>(p.H[m] + (size_t)fid * 8) = h;
  *reinterpret_cast<uint4*>(p.L[m] + (size_t)fid * 8) = l;
}

// ---------------------------------------------------------------------------
// GEMM: P[ks][64][4096] partial = X[64][krange] @ W[krange][4096]
// Block: 4 waves (256 thr), 64 cols (16/wave), all 64 rows, KR = TL/KSplit.
// Tile = K32 x 64 cols (16 KB LDS: B 8K fp32 [32k][64c], Ah 4K, Al 4K packed).
// Triple-buffered, 2-deep prefetch, 4 gload_lds per wave per tile.
// ---------------------------------------------------------------------------
struct GemmArgs {
  const u16* Ah[3];
  const u16* Al[3];
  const float* W[3];
  float* P[3];
};

template <int KSplit, int NMat>
__global__ __launch_bounds__(256, 3) void mfma_gemm(GemmArgs ga) {
  constexpr int KR = TL / KSplit;   // K range per block
  constexpr int NT = KR / 32;       // K32 tiles (32 or 16)
  constexpr int NWG = NMat * KSplit * 64;
  constexpr int TSZ = 16384;
  static_assert(NWG % 8 == 0, "xcd swizzle needs NWG%8==0");
  static_assert(NT >= 2, "pipeline needs >=2 tiles");
  __shared__ __align__(16) char sb[3 * TSZ];  // 48 KiB -> 3 blocks/CU

  const int tid = threadIdx.x;
  const int lane = tid & 63;
  const int w = tid >> 6;                    // wave 0..3
  const int l15 = lane & 15, kg = lane >> 4;

  // Bijective XCD swizzle: contiguous work range per XCD (L2 A locality).
  const int swz = (blockIdx.x & 7) * (NWG / 8) + (blockIdx.x >> 3);
  const int mat = swz / (KSplit * 64);
  const int r = swz % (KSplit * 64);
  const int ks = r >> 6;
  const int ct = r & 63;
  const int k0 = ks * KR;
  const int tg0 = ks * NT;                   // global K32 chunk base
  const int colg0 = ct * 64;                 // block's 64-col base

  const float* Wm = ga.W[mat];
  const u16* Agh = ga.Ah[mat];
  const u16* Agl = ga.Al[mat];

  // Per-tile staging: 4 gload_lds per wave (2 B + 2 A), all counted in vmcnt.
  const int half = w >> 1;                   // 0: stage Ah, 1: stage Al
  const int part = w & 1;                    // fragment pair within half
  const u16* Abase = (half ? Agl : Agh) + (size_t)part * 1024 + lane * 8;
  char* const adst0 = sb + 8192 + half * 4096 + part * 2048;

  auto STAGE = [&](char* buf, int t) {
    const int kb = k0 + t * 32;
    // B: wave w stages k-rows [w*8, w*8+8), 2 x 1KB.
#pragma unroll
    for (int i = 0; i < 2; ++i) {
      const int krow = w * 8 + i * 4 + (lane >> 4);
      const float* gsrc = Wm + (size_t)(kb + krow) * TL + colg0 + (lane & 15) * 4;
      GLOAD_LDS(gsrc, buf + (w * 8 + i * 4) * 256);
    }
    // A: wave w stages 2 packed fragments of its half.
    const u16* asrc = Abase + (size_t)(tg0 + t) * 2048;
    char* adst = (buf - sb) + adst0;
    GLOAD_LDS(asrc, adst);
    GLOAD_LDS(asrc + 512, adst + 1024);
  };

  f32x4 acc[4] = {};

  auto COMPUTE = [&](const char* buf) {
    const float* Bf = (const float*)buf;
    const char* Ahb = buf + 8192;
    const char* Alb = buf + 12288;
    float f[8];
#pragma unroll
    for (int e = 0; e < 8; ++e) f[e] = Bf[(kg * 8 + e) * 64 + w * 16 + l15];
    B8 bh, bl;
#pragma unroll
    for (int e = 0; e < 4; ++e)
      split_pair(f[2 * e], f[2 * e + 1], bh.u[e], bl.u[e]);
#pragma unroll
    for (int rt = 0; rt < 4; ++rt) {
      const bf16x8 ah = *(const bf16x8*)(Ahb + rt * 1024 + lane * 16);
      const bf16x8 al = *(const bf16x8*)(Alb + rt * 1024 + lane * 16);
      acc[rt] = __builtin_amdgcn_mfma_f32_16x16x32_bf16(ah, bh.v, acc[rt], 0, 0, 0);
      acc[rt] = __builtin_amdgcn_mfma_f32_16x16x32_bf16(ah, bl.v, acc[rt], 0, 0, 0);
      acc[rt] = __builtin_amdgcn_mfma_f32_16x16x32_bf16(al, bh.v, acc[rt], 0, 0, 0);
    }
  };

  STAGE(sb, 0);
  STAGE(sb + TSZ, 1);

#pragma unroll 1
  for (int t = 0; t < NT; ++t) {
    char* cur = sb + (t % 3) * TSZ;
    if (t + 2 < NT) {
      STAGE(sb + ((t + 2) % 3) * TSZ, t + 2);
      // tiles t+1, t+2 in flight (8 gloads); tile t must be resident.
      asm volatile("s_waitcnt vmcnt(8)" ::: "memory");
    } else if (t + 2 == NT) {
      asm volatile("s_waitcnt vmcnt(4)" ::: "memory");
    } else {
      asm volatile("s_waitcnt vmcnt(0)" ::: "memory");
    }
    __builtin_amdgcn_s_barrier();   // all waves: tile t fully in LDS
    COMPUTE(cur);
    __builtin_amdgcn_s_barrier();   // all reads of tile t done before overwrite
  }

  // C/D: col = lane&15, row = (lane>>4)*4 + reg (per 16-row tile rt)
  float* Pp = ga.P[mat] + ((size_t)ks * NB) * TL + colg0 + w * 16 + l15;
#pragma unroll
  for (int rt = 0; rt < 4; ++rt)
#pragma unroll
    for (int j = 0; j < 4; ++j)
      Pp[(size_t)(rt * 16 + kg * 4 + j) * TL] = acc[rt][j];
}

// ---------------------------------------------------------------------------
// dist[b,h] = softmax_h(cossim(qh[b,h,:], kh[b,h,:])); sums KSQ partials+bias.
// ---------------------------------------------------------------------------
__global__ __launch_bounds__(64) void dist_kernel(
    const float* __restrict__ Pq, const float* __restrict__ Pk,
    const float* __restrict__ bq, const float* __restrict__ bk,
    float* __restrict__ dist) {
  const int b = blockIdx.x;
  const int h = threadIdx.x;
  float num = 0.f, qq = 0.f, kk = 0.f;
#pragma unroll
  for (int d = 0; d < 64; d += 4) {
    f32x4 qv = *(const f32x4*)&bq[h * 64 + d];
    f32x4 kv = *(const f32x4*)&bk[h * 64 + d];
#pragma unroll
    for (int s = 0; s < KSQ; ++s) {
      qv += *(const f32x4*)&Pq[((size_t)s * NB + b) * TL + h * 64 + d];
      kv += *(const f32x4*)&Pk[((size_t)s * NB + b) * TL + h * 64 + d];
    }
#pragma unroll
    for (int e = 0; e < 4; ++e) {
      num += qv[e] * kv[e];
      qq += qv[e] * qv[e];
      kk += kv[e] * kv[e];
    }
  }
  const float den = fmaxf(sqrtf(qq) * sqrtf(kk), 1e-8f);
  float s = num / den;
  float m = s;
#pragma unroll
  for (int off = 32; off; off >>= 1) m = fmaxf(m, __shfl_xor(m, off));
  const float e = expf(s - m);
  float sum = e;
#pragma unroll
  for (int off = 32; off; off >>= 1) sum += __shfl_xor(sum, off);
  dist[b * 64 + h] = e / sum;
}

// ---------------------------------------------------------------------------
// attn row i: vrow = sum(Pv parts)+bv; attn[i,c] = sum_h ds[j,h]*vrow[h*64+d]
// Emits hi/lo bf16 in PACKED fragment order (A-operand of the output GEMM).
// ---------------------------------------------------------------------------
__global__ __launch_bounds__(256) void attn_kernel(
    const float* __restrict__ Pv, const float* __restrict__ bv,
    const float* __restrict__ dist, u16* __restrict__ Ah,
    u16* __restrict__ Al) {
  const int i = blockIdx.x;
  __shared__ float vrow[TL];
  __shared__ float ds[NB * NB];
  const int tid = threadIdx.x;
#pragma unroll
  for (int f = tid; f < 1024; f += 256) {
    f32x4 v = *(const f32x4*)&bv[f * 4];
#pragma unroll
    for (int s = 0; s < KSQ; ++s)
      v += *(const f32x4*)&Pv[((size_t)s * NB + i) * TL + f * 4];
    *reinterpret_cast<f32x4*>(&vrow[f * 4]) = v;
    *reinterpret_cast<f32x4*>(&ds[f * 4]) =
        *reinterpret_cast<const f32x4*>(&dist[f * 4]);
  }
  __syncthreads();
  const int rt = i >> 4, l15r = i & 15;
#pragma unroll
  for (int s = 0; s < 16; ++s) {
    const int c = tid + 256 * s;
    const int j = c >> 6, d = c & 63;
    float sum = 0.f;
#pragma unroll
    for (int h = 0; h < 64; ++h) sum += ds[j * 64 + h] * vrow[h * 64 + d];
    const uint32 u = __float_as_uint(sum);
    const float lo = sum - __uint_as_float(u & 0xffff0000u);
    // packed index: T=c>>5, kg=(c>>3)&3, e=c&7
    const uint32 off =
        (((uint32)(c >> 5) * 4 + rt) * 64 + ((c >> 3) & 3) * 16 + l15r) * 8 +
        (c & 7);
    Ah[off] = (u16)(u >> 16);
    Al[off] = (u16)(__float_as_uint(lo) >> 16);
  }
}

// out = sum over KSO partials + bo
__global__ __launch_bounds__(256) void reduce_kernel(
    const float* __restrict__ Po, const float* __restrict__ bo,
    float* __restrict__ out) {
  const int idx = (blockIdx.x * 256 + threadIdx.x) * 4;
  f32x4 v = *(const f32x4*)&bo[idx & (TL - 1)];
#pragma unroll
  for (int s = 0; s < KSO; ++s)
    v += *(const f32x4*)&Po[(size_t)s * NB * TL + idx];
  *reinterpret_cast<f32x4*>(&out[idx]) = v;
}

extern "C" void kernel_launch(void* const* d_in, const int* in_sizes, int n_in,
                              void* d_out, int out_size, void* d_ws,
                              size_t ws_size, hipStream_t stream) {
  const float* q  = (const float*)d_in[0];
  const float* k  = (const float*)d_in[1];
  const float* v  = (const float*)d_in[2];
  const float* Wq = (const float*)d_in[3];
  const float* bq = (const float*)d_in[4];
  const float* Wk = (const float*)d_in[5];
  const float* bk = (const float*)d_in[6];
  const float* Wv = (const float*)d_in[7];
  const float* bv = (const float*)d_in[8];
  const float* Wo = (const float*)d_in[9];
  const float* bo = (const float*)d_in[10];
  float* out = (float*)d_out;

  char* ws = (char*)d_ws;
  const size_t HB = 512u * 1024u;
  u16* qAh = (u16*)(ws + 0 * HB);
  u16* qAl = (u16*)(ws + 1 * HB);
  u16* kAh = (u16*)(ws + 2 * HB);
  u16* kAl = (u16*)(ws + 3 * HB);
  u16* vAh = (u16*)(ws + 4 * HB);
  u16* vAl = (u16*)(ws + 5 * HB);
  u16* aAh = (u16*)(ws + 6 * HB);
  u16* aAl = (u16*)(ws + 7 * HB);
  float* Pq = (float*)(ws + (4u << 20));   // 4 MiB (KSQ=4 partials)
  float* Pk = (float*)(ws + (8u << 20));   // 4 MiB
  float* Pv = (float*)(ws + (12u << 20));  // 4 MiB
  // Po (KSO=8, 8 MiB) aliases [Pq,Pk]: both fully consumed before O-GEMM.
  float* Po = Pq;
  float* dist = (float*)(ws + (16u << 20));  // 16 KiB

  // 1. split q,k,v into packed hi/lo bf16 fragments
  Ptrs3 p3;
  p3.X[0] = q; p3.X[1] = k; p3.X[2] = v;
  p3.H[0] = qAh; p3.H[1] = kAh; p3.H[2] = vAh;
  p3.L[0] = qAl; p3.L[1] = kAl; p3.L[2] = vAl;
  prep_kernel<<<dim3(128, 3), 256, 0, stream>>>(p3);

  // 2. QKV projections: 3 mats x KSQ x 64 coltiles = 768 blocks (3/CU exact)
  GemmArgs gq;
  gq.Ah[0] = qAh; gq.Ah[1] = kAh; gq.Ah[2] = vAh;
  gq.Al[0] = qAl; gq.Al[1] = kAl; gq.Al[2] = vAl;
  gq.W[0] = Wq; gq.W[1] = Wk; gq.W[2] = Wv;
  gq.P[0] = Pq; gq.P[1] = Pk; gq.P[2] = Pv;
  mfma_gemm<KSQ, 3><<<3 * KSQ * 64, 256, 0, stream>>>(gq);

  // 3. cosine-sim + softmax
  dist_kernel<<<NB, 64, 0, stream>>>(Pq, Pk, bq, bk, dist);

  // 4. attention mix -> packed bf16 hi/lo attn
  attn_kernel<<<NB, 256, 0, stream>>>(Pv, bv, dist, aAh, aAl);

  // 5. output GEMM: KSO x 64 coltiles = 512 blocks (2/CU)
  GemmArgs go;
  go.Ah[0] = aAh; go.Ah[1] = aAh; go.Ah[2] = aAh;
  go.Al[0] = aAl; go.Al[1] = aAl; go.Al[2] = aAl;
  go.W[0] = Wo; go.W[1] = Wo; go.W[2] = Wo;
  go.P[0] = Po; go.P[1] = Po; go.P[2] = Po;
  mfma_gemm<KSO, 1><<<KSO * 64, 256, 0, stream>>>(go);

  // 6. final reduce + bias
  reduce_kernel<<<256, 256, 0, stream>>>(Po, bo, out);
}

// Round 8
// 105.412 us; speedup vs baseline: 3.0340x; 1.0740x over previous
//
#include <hip/hip_runtime.h>
#include <hip/hip_bf16.h>
#include <math.h>

// B=64, M=1, L=E=4096, H=64, DK=64.
// LDS-staged skinny GEMM. All staging via global_load_lds (homogeneous vmem
// stream -> counted vmcnt race-free), triple-buffered tiles, 2-deep prefetch.
// Round-8 geometry: 8-wave blocks, wide column tiles (256 QKV / 128 O) so
// each k-row is staged as a 1KB/512B contiguous chunk (DRAM-page friendly)
// and A-staging overhead drops to 25%/50%. bf16 split-precision MFMA.

#define TL 4096
#define NB 64
#define KSQ 4   // k-splits for QKV projections
#define KSO 8   // k-splits for output GEMM

typedef float f32x4 __attribute__((ext_vector_type(4)));
typedef short bf16x8 __attribute__((ext_vector_type(8)));
typedef unsigned int uint32;
typedef unsigned short u16;

union B8 { uint32 u[4]; bf16x8 v; };

// global_load_lds: per-lane global src, LDS dest = wave-uniform base + lane*16.
#define GLOAD_LDS(g, l)                                                        \
  __builtin_amdgcn_global_load_lds(                                           \
      (const __attribute__((address_space(1))) void*)(g),                     \
      (__attribute__((address_space(3))) void*)(l), 16, 0, 0)

#define WAITCNT(n) asm volatile("s_waitcnt vmcnt(" #n ")" ::: "memory")

// Split two fp32 into packed hi-bf16 pair and lo-bf16 pair (truncation).
__device__ __forceinline__ void split_pair(float f0, float f1, uint32& hp,
                                           uint32& lp) {
  uint32 u0 = __float_as_uint(f0), u1 = __float_as_uint(f1);
  hp = (u0 >> 16) | (u1 & 0xffff0000u);
  float l0 = f0 - __uint_as_float(u0 & 0xffff0000u);
  float l1 = f1 - __uint_as_float(u1 & 0xffff0000u);
  lp = (__float_as_uint(l0) >> 16) | (__float_as_uint(l1) & 0xffff0000u);
}

// Packed-A: fragment fi = T*4+rt (T = global K32 chunk, rt = 16-row group),
// lane = kg*16+l15 holds row rt*16+l15, k = T*32+kg*8+e. u16 off = fi*512+lane*8.

// ---------------------------------------------------------------------------
// prep: fp32 X[64][4096] -> packed Ah, Al (bf16 fragment order)
// ---------------------------------------------------------------------------
struct Ptrs3 { const float* X[3]; u16* H[3]; u16* L[3]; };

__global__ __launch_bounds__(256) void prep_kernel(Ptrs3 p) {
  const int m = blockIdx.y;
  const int fid = blockIdx.x * 256 + threadIdx.x;  // 0..32767
  const int lane = fid & 63, fi = fid >> 6;        // fi 0..511
  const int t = fi >> 2, rt = fi & 3;
  const int row = rt * 16 + (lane & 15);
  const int k0 = t * 32 + (lane >> 4) * 8;
  const float* src = p.X[m] + (size_t)row * TL + k0;
  const float4 f0 = *reinterpret_cast<const float4*>(src);
  const float4 f1 = *reinterpret_cast<const float4*>(src + 4);
  uint4 h, l;
  split_pair(f0.x, f0.y, h.x, l.x);
  split_pair(f0.z, f0.w, h.y, l.y);
  split_pair(f1.x, f1.y, h.z, l.z);
  split_pair(f1.z, f1.w, h.w, l.w);
  *reinterpret_cast<uint4*>(p.H[m] + (size_t)fid * 8) = h;
  *reinterpret_cast<uint4*>(p.L[m] + (size_t)fid * 8) = l;
}

// ---------------------------------------------------------------------------
// GEMM: P[ks][64][4096] partial = X[64][krange] @ W[krange][4096]
// Block: 8 waves (512 thr), CB cols, all 64 rows, KR = TL/KSplit.
// Tile = K32 x CB: B = CB*128 bytes (each k-row one contiguous CB*4-byte
// chunk), A = 8KB packed fragments. Triple-buffered, 2-deep prefetch.
// Per wave per tile: CB/64 B-gloads + 1 A-gload, all 1KB, all counted.
// ---------------------------------------------------------------------------
struct GemmArgs {
  const u16* Ah[3];
  const u16* Al[3];
  const float* W[3];
  float* P[3];
};

template <int KSplit, int NMat, int CB>
__global__ __launch_bounds__(512, 2) void mfma_gemm(GemmArgs ga) {
  constexpr int KR = TL / KSplit;   // K range per block
  constexpr int NT = KR / 32;       // K32 tiles
  constexpr int NCG = TL / CB;      // column groups
  constexpr int NWG = NMat * KSplit * NCG;
  constexpr int BSZ = CB * 128;     // B bytes per tile
  constexpr int TSZ = BSZ + 8192;   // + A hi/lo
  constexpr int NBG = CB / 64;      // B gloads per wave per tile (4 or 2)
  constexpr int LPR = CB / 4;       // lanes per k-row (64 or 32)
  constexpr int SUB = CB / 128;     // 16-col subtiles per wave (2 or 1)
  static_assert(NWG % 8 == 0, "xcd swizzle needs NWG%8==0");
  static_assert(NT >= 3, "pipeline needs >=3 tiles");
  __shared__ __align__(16) char sb[3 * TSZ];

  const int tid = threadIdx.x;
  const int lane = tid & 63;
  const int w = tid >> 6;                    // wave 0..7
  const int l15 = lane & 15, kg = lane >> 4;

  // Bijective XCD swizzle: contiguous work range per XCD (L2 A locality).
  const int swz = (blockIdx.x & 7) * (NWG / 8) + (blockIdx.x >> 3);
  const int mat = swz / (KSplit * NCG);
  const int r = swz % (KSplit * NCG);
  const int ks = r / NCG;
  const int cg = r % NCG;
  const int k0 = ks * KR;
  const int tg0 = ks * NT;                   // global K32 chunk base
  const int cg0 = cg * CB;                   // block's column base

  const float* Wm = ga.W[mat];
  const u16* Agh = ga.Ah[mat];
  const u16* Agl = ga.Al[mat];

  // A: wave w<4 stages hi fragment rt=w; w>=4 stages lo fragment rt=w-4.
  const u16* Asrc0 = (w < 4 ? Agh : Agl) + (size_t)(w & 3) * 512 + lane * 8;
  const int adst = BSZ + (w < 4 ? 0 : 4096) + (w & 3) * 1024;

  auto STAGE = [&](char* buf, int t) {
    const int kb = k0 + t * 32;
    // B: NBG gloads, each one or two full k-rows (contiguous CB*4B chunks).
#pragma unroll
    for (int i = 0; i < NBG; ++i) {
      const int gl = w * NBG + i;
      const float* gsrc = Wm + (size_t)(kb + gl * (64 / LPR) + lane / LPR) * TL +
                          cg0 + (lane % LPR) * 4;
      GLOAD_LDS(gsrc, buf + gl * 1024);
    }
    // A: one packed fragment (1KB).
    GLOAD_LDS(Asrc0 + (size_t)(tg0 + t) * 2048, buf + adst);
  };

  f32x4 acc[SUB][4] = {};

  auto COMPUTE = [&](const char* buf) {
    const float* Bf = (const float*)buf;
    const char* Ahb = buf + BSZ;
    const char* Alb = buf + BSZ + 4096;
    bf16x8 ah[4], al[4];
#pragma unroll
    for (int rt = 0; rt < 4; ++rt) {
      ah[rt] = *(const bf16x8*)(Ahb + rt * 1024 + lane * 16);
      al[rt] = *(const bf16x8*)(Alb + rt * 1024 + lane * 16);
    }
#pragma unroll
    for (int c2 = 0; c2 < SUB; ++c2) {
      const int wcol = w * (CB / 8) + c2 * 16;
      float f[8];
#pragma unroll
      for (int e = 0; e < 8; ++e) f[e] = Bf[(kg * 8 + e) * CB + wcol + l15];
      B8 bh, bl;
#pragma unroll
      for (int e = 0; e < 4; ++e)
        split_pair(f[2 * e], f[2 * e + 1], bh.u[e], bl.u[e]);
#pragma unroll
      for (int rt = 0; rt < 4; ++rt) {
        acc[c2][rt] = __builtin_amdgcn_mfma_f32_16x16x32_bf16(ah[rt], bh.v, acc[c2][rt], 0, 0, 0);
        acc[c2][rt] = __builtin_amdgcn_mfma_f32_16x16x32_bf16(ah[rt], bl.v, acc[c2][rt], 0, 0, 0);
        acc[c2][rt] = __builtin_amdgcn_mfma_f32_16x16x32_bf16(al[rt], bh.v, acc[c2][rt], 0, 0, 0);
      }
    }
  };

  char* cur = sb;
  char* nxt = sb + TSZ;
  char* stg = sb + 2 * TSZ;
  STAGE(cur, 0);
  STAGE(nxt, 1);

#pragma unroll 1
  for (int t = 0; t < NT; ++t) {
    if (t + 2 < NT) {
      STAGE(stg, t + 2);
      // tiles t+1,t+2 in flight (2*(NBG+1) gloads); tile t must be resident.
      if constexpr (NBG == 4) WAITCNT(10); else WAITCNT(6);
    } else if (t + 2 == NT) {
      if constexpr (NBG == 4) WAITCNT(5); else WAITCNT(3);
    } else {
      WAITCNT(0);
    }
    __builtin_amdgcn_s_barrier();   // all waves: tile t fully in LDS
    COMPUTE(cur);
    __builtin_amdgcn_s_barrier();   // all reads done before overwrite
    char* tmp = cur; cur = nxt; nxt = stg; stg = tmp;
  }

  // C/D: col = lane&15, row = (lane>>4)*4 + reg (per 16-row tile rt)
  float* Pp = ga.P[mat] + ((size_t)ks * NB) * TL + cg0 + w * (CB / 8) + l15;
#pragma unroll
  for (int c2 = 0; c2 < SUB; ++c2)
#pragma unroll
    for (int rt = 0; rt < 4; ++rt)
#pragma unroll
      for (int j = 0; j < 4; ++j)
        Pp[(size_t)(rt * 16 + kg * 4 + j) * TL + c2 * 16] = acc[c2][rt][j];
}

// ---------------------------------------------------------------------------
// dist[b,h] = softmax_h(cossim(qh[b,h,:], kh[b,h,:])); sums KSQ partials+bias.
// ---------------------------------------------------------------------------
__global__ __launch_bounds__(64) void dist_kernel(
    const float* __restrict__ Pq, const float* __restrict__ Pk,
    const float* __restrict__ bq, const float* __restrict__ bk,
    float* __restrict__ dist) {
  const int b = blockIdx.x;
  const int h = threadIdx.x;
  float num = 0.f, qq = 0.f, kk = 0.f;
#pragma unroll
  for (int d = 0; d < 64; d += 4) {
    f32x4 qv = *(const f32x4*)&bq[h * 64 + d];
    f32x4 kv = *(const f32x4*)&bk[h * 64 + d];
#pragma unroll
    for (int s = 0; s < KSQ; ++s) {
      qv += *(const f32x4*)&Pq[((size_t)s * NB + b) * TL + h * 64 + d];
      kv += *(const f32x4*)&Pk[((size_t)s * NB + b) * TL + h * 64 + d];
    }
#pragma unroll
    for (int e = 0; e < 4; ++e) {
      num += qv[e] * kv[e];
      qq += qv[e] * qv[e];
      kk += kv[e] * kv[e];
    }
  }
  const float den = fmaxf(sqrtf(qq) * sqrtf(kk), 1e-8f);
  float s = num / den;
  float m = s;
#pragma unroll
  for (int off = 32; off; off >>= 1) m = fmaxf(m, __shfl_xor(m, off));
  const float e = expf(s - m);
  float sum = e;
#pragma unroll
  for (int off = 32; off; off >>= 1) sum += __shfl_xor(sum, off);
  dist[b * 64 + h] = e / sum;
}

// ---------------------------------------------------------------------------
// attn row i: vrow = sum(Pv parts)+bv; attn[i,c] = sum_h ds[j,h]*vrow[h*64+d]
// Emits hi/lo bf16 in PACKED fragment order (A-operand of the output GEMM).
// ---------------------------------------------------------------------------
__global__ __launch_bounds__(256) void attn_kernel(
    const float* __restrict__ Pv, const float* __restrict__ bv,
    const float* __restrict__ dist, u16* __restrict__ Ah,
    u16* __restrict__ Al) {
  const int i = blockIdx.x;
  __shared__ float vrow[TL];
  __shared__ float ds[NB * NB];
  const int tid = threadIdx.x;
#pragma unroll
  for (int f = tid; f < 1024; f += 256) {
    f32x4 v = *(const f32x4*)&bv[f * 4];
#pragma unroll
    for (int s = 0; s < KSQ; ++s)
      v += *(const f32x4*)&Pv[((size_t)s * NB + i) * TL + f * 4];
    *reinterpret_cast<f32x4*>(&vrow[f * 4]) = v;
    *reinterpret_cast<f32x4*>(&ds[f * 4]) =
        *reinterpret_cast<const f32x4*>(&dist[f * 4]);
  }
  __syncthreads();
  const int rt = i >> 4, l15r = i & 15;
#pragma unroll
  for (int s = 0; s < 16; ++s) {
    const int c = tid + 256 * s;
    const int j = c >> 6, d = c & 63;
    float sum = 0.f;
#pragma unroll
    for (int h = 0; h < 64; ++h) sum += ds[j * 64 + h] * vrow[h * 64 + d];
    const uint32 u = __float_as_uint(sum);
    const float lo = sum - __uint_as_float(u & 0xffff0000u);
    // packed index: T=c>>5, kg=(c>>3)&3, e=c&7
    const uint32 off =
        (((uint32)(c >> 5) * 4 + rt) * 64 + ((c >> 3) & 3) * 16 + l15r) * 8 +
        (c & 7);
    Ah[off] = (u16)(u >> 16);
    Al[off] = (u16)(__float_as_uint(lo) >> 16);
  }
}

// out = sum over KSO partials + bo
__global__ __launch_bounds__(256) void reduce_kernel(
    const float* __restrict__ Po, const float* __restrict__ bo,
    float* __restrict__ out) {
  const int idx = (blockIdx.x * 256 + threadIdx.x) * 4;
  f32x4 v = *(const f32x4*)&bo[idx & (TL - 1)];
#pragma unroll
  for (int s = 0; s < KSO; ++s)
    v += *(const f32x4*)&Po[(size_t)s * NB * TL + idx];
  *reinterpret_cast<f32x4*>(&out[idx]) = v;
}

extern "C" void kernel_launch(void* const* d_in, const int* in_sizes, int n_in,
                              void* d_out, int out_size, void* d_ws,
                              size_t ws_size, hipStream_t stream) {
  const float* q  = (const float*)d_in[0];
  const float* k  = (const float*)d_in[1];
  const float* v  = (const float*)d_in[2];
  const float* Wq = (const float*)d_in[3];
  const float* bq = (const float*)d_in[4];
  const float* Wk = (const float*)d_in[5];
  const float* bk = (const float*)d_in[6];
  const float* Wv = (const float*)d_in[7];
  const float* bv = (const float*)d_in[8];
  const float* Wo = (const float*)d_in[9];
  const float* bo = (const float*)d_in[10];
  float* out = (float*)d_out;

  char* ws = (char*)d_ws;
  const size_t HB = 512u * 1024u;
  u16* qAh = (u16*)(ws + 0 * HB);
  u16* qAl = (u16*)(ws + 1 * HB);
  u16* kAh = (u16*)(ws + 2 * HB);
  u16* kAl = (u16*)(ws + 3 * HB);
  u16* vAh = (u16*)(ws + 4 * HB);
  u16* vAl = (u16*)(ws + 5 * HB);
  u16* aAh = (u16*)(ws + 6 * HB);
  u16* aAl = (u16*)(ws + 7 * HB);
  float* Pq = (float*)(ws + (4u << 20));   // 4 MiB (KSQ=4 partials)
  float* Pk = (float*)(ws + (8u << 20));   // 4 MiB
  float* Pv = (float*)(ws + (12u << 20));  // 4 MiB
  // Po (KSO=8, 8 MiB) aliases [Pq,Pk]: both fully consumed before O-GEMM.
  float* Po = Pq;
  float* dist = (float*)(ws + (16u << 20));  // 16 KiB

  // 1. split q,k,v into packed hi/lo bf16 fragments
  Ptrs3 p3;
  p3.X[0] = q; p3.X[1] = k; p3.X[2] = v;
  p3.H[0] = qAh; p3.H[1] = kAh; p3.H[2] = vAh;
  p3.L[0] = qAl; p3.L[1] = kAl; p3.L[2] = vAl;
  prep_kernel<<<dim3(128, 3), 256, 0, stream>>>(p3);

  // 2. QKV projections: 3 mats x 4 ksplits x 16 colgroups(256c) = 192 blocks
  GemmArgs gq;
  gq.Ah[0] = qAh; gq.Ah[1] = kAh; gq.Ah[2] = vAh;
  gq.Al[0] = qAl; gq.Al[1] = kAl; gq.Al[2] = vAl;
  gq.W[0] = Wq; gq.W[1] = Wk; gq.W[2] = Wv;
  gq.P[0] = Pq; gq.P[1] = Pk; gq.P[2] = Pv;
  mfma_gemm<KSQ, 3, 256><<<3 * KSQ * 16, 512, 0, stream>>>(gq);

  // 3. cosine-sim + softmax
  dist_kernel<<<NB, 64, 0, stream>>>(Pq, Pk, bq, bk, dist);

  // 4. attention mix -> packed bf16 hi/lo attn
  attn_kernel<<<NB, 256, 0, stream>>>(Pv, bv, dist, aAh, aAl);

  // 5. output GEMM: 8 ksplits x 32 colgroups(128c) = 256 blocks
  GemmArgs go;
  go.Ah[0] = aAh; go.Ah[1] = aAh; go.Ah[2] = aAh;
  go.Al[0] = aAl; go.Al[1] = aAl; go.Al[2] = aAl;
  go.W[0] = Wo; go.W[1] = Wo; go.W[2] = Wo;
  go.P[0] = Po; go.P[1] = Po; go.P[2] = Po;
  mfma_gemm<KSO, 1, 128><<<KSO * 32, 512, 0, stream>>>(go);

  // 6. final reduce + bias
  reduce_kernel<<<256, 256, 0, stream>>>(Po, bo, out);
}